// Round 5
// baseline (4639.861 us; speedup 1.0000x reference)
//
#include <hip/hip_runtime.h>
#include <stdint.h>
#include <stddef.h>

#define T_ 256
#define H_ 128

typedef __attribute__((ext_vector_type(8))) short short8;
typedef __attribute__((ext_vector_type(4))) float f32x4;

#define MFMA16(a,b,c) __builtin_amdgcn_mfma_f32_16x16x32_bf16(a,b,c,0,0,0)

// ---- ws layout (bytes) ----
#define WS_MB0      0            // 64 blocks * 8192 B (16x64 u64)
#define WS_MB1      524288
#define WS_MB_BYTES 1048576
#define WS_HTH      1048576      // hT hi plane: 512*128 u16
#define WS_HTL      (1048576+131072)

// ---- LDS layout (both scan kernels) ----
// [0,131072): weight-lo (enc: Whh-lo) / Whh1 hi+lo (dec) fragments
// u buffers: 16 rows x 264 u16 (528 B = 33x16B, odd multiple -> conflict-min)
#define U_H 131072
#define U_L (131072+8448)
#define SCAN_SMEM 147968

__device__ __forceinline__ uint16_t bf16rne(float f){
  uint32_t u = __float_as_uint(f);
  uint32_t r = u + 0x7FFFu + ((u >> 16) & 1u);
  return (uint16_t)(r >> 16);
}
__device__ __forceinline__ float fast_sig(float x){
  return __builtin_amdgcn_rcpf(1.0f + __expf(-x));
}
__device__ __forceinline__ float fast_tanh(float x){
  float ax = fabsf(x);
  float e  = __expf(-2.0f * ax);
  float t  = (1.0f - e) * __builtin_amdgcn_rcpf(1.0f + e);
  return copysignf(t, x);
}
__device__ __forceinline__ f32x4 splat4(float v){ f32x4 r={v,v,v,v}; return r; }

__device__ __forceinline__ void splitf(float v, uint16_t& h, uint16_t& l){
  h = bf16rne(v);
  float hf = __uint_as_float((uint32_t)h << 16);
  l = bf16rne(v - hf);
}
__device__ __forceinline__ void load_frag2(const float* __restrict__ rowp, int koff,
                                           short8& h, short8& l){
  #pragma unroll
  for(int j=0;j<8;j++){
    uint16_t hb, lb; splitf(rowp[koff+j], hb, lb);
    h[j]=(short)hb; l[j]=(short)lb;
  }
}
__device__ __forceinline__ void packf4(f32x4 v, uint64_t& ph, uint64_t& pl){
  ph=0; pl=0;
  #pragma unroll
  for(int j=0;j<4;j++){
    uint16_t hb,lb; splitf(v[j],hb,lb);
    ph |= (uint64_t)hb << (16*j);
    pl |= (uint64_t)lb << (16*j);
  }
}

// =====================  ENCODER  =====================
// 32 blocks x 256 thr (4 waves, 1 block/CU -> 1 wave/SIMD -> 512-reg budget).
// Wave w owns h-columns [32w,32w+32) = groups gg: gate=gg>>1, ngl=gg&1,
// col=(w*2+ngl)*16+m. Weights WiH/WiL/WhH in VGPRs (384), Whh-lo in LDS.
// u K-slots: [0,128)=input, [128,256)=h(latest).
__global__ __launch_bounds__(256,1) void enc_kernel(
    const float* __restrict__ x,
    const float* __restrict__ Wih0, const float* __restrict__ Whh0,
    const float* __restrict__ bih0, const float* __restrict__ bhh0,
    const float* __restrict__ Wih1, const float* __restrict__ Whh1,
    const float* __restrict__ bih1, const float* __restrict__ bhh1,
    uint16_t* __restrict__ plh, uint16_t* __restrict__ pll,
    uint16_t* __restrict__ hTh, uint16_t* __restrict__ hTl)
{
  extern __shared__ __align__(16) char smem[];
  const int tid=threadIdx.x, w=tid>>6, l=tid&63, q=l>>4, m=l&15;
  const int rb = blockIdx.x*16;
  uint16_t* uh=(uint16_t*)(smem+U_H);
  uint16_t* ul=(uint16_t*)(smem+U_L);
  const int srow=tid>>4, sc8=(tid&15)*8;

  short8 WiH[8][4], WiL[8][4], WhH[8][4];
  float bias[8], c[2][4];

  auto loadW = [&](const float* Wih,const float* Whh,const float* bi,const float* bh){
    #pragma unroll
    for(int gg=0;gg<8;gg++){
      const int gate=gg>>1, ngl=gg&1;
      const int row = gate*128 + (w*2+ngl)*16 + m;
      const float* rih = Wih + (size_t)row*128;
      const float* rhh = Whh + (size_t)row*128;
      #pragma unroll
      for(int kt=0;kt<4;kt++){
        load_frag2(rih, kt*32+q*8, WiH[gg][kt], WiL[gg][kt]);
        short8 hh,hl; load_frag2(rhh, kt*32+q*8, hh, hl);
        WhH[gg][kt]=hh;
        *(short8*)(smem + (size_t)(((w*8+gg)*4+kt)*64+l)*16) = hl;
      }
      bias[gg]=bi[row]+bh[row];
    }
  };
  auto zeroH = [&](){
    *(uint64_t*)(uh + srow*264 + 128 + sc8) = 0ull;
    *(uint64_t*)(uh + srow*264 + 128 + sc8 + 4) = 0ull;
    *(uint64_t*)(ul + srow*264 + 128 + sc8) = 0ull;
    *(uint64_t*)(ul + srow*264 + 128 + sc8 + 4) = 0ull;
  };
  auto scat = [&](uint64_t ph0, uint64_t pl0, uint64_t ph1, uint64_t pl1){
    *(uint64_t*)(uh + srow*264 + sc8)     = ph0;
    *(uint64_t*)(uh + srow*264 + sc8 + 4) = ph1;
    *(uint64_t*)(ul + srow*264 + sc8)     = pl0;
    *(uint64_t*)(ul + srow*264 + sc8 + 4) = pl1;
  };

  auto scan = [&](bool first){
    #pragma unroll 1
    for(int t=0;t<T_;t++){
      uint64_t nh0=0,nl0=0,nh1=0,nl1=0;
      const bool dox = (t+1<T_);
      if(dox){
        if(first){
          const float* src = x + ((size_t)(rb+srow)*T_+(t+1))*128 + sc8;
          f32x4 v0=*(const f32x4*)src, v1=*(const f32x4*)(src+4);
          packf4(v0,nh0,nl0); packf4(v1,nh1,nl1);
        } else {
          size_t gi=((size_t)(rb+srow)*T_+(t+1))*128+sc8;
          nh0=*(const uint64_t*)(plh+gi);   nh1=*(const uint64_t*)(plh+gi+4);
          nl0=*(const uint64_t*)(pll+gi);   nl1=*(const uint64_t*)(pll+gi+4);
        }
      }
      f32x4 acc[8];
      #pragma unroll
      for(int gg=0;gg<8;gg++) acc[gg]=splat4(bias[gg]);
      #pragma unroll
      for(int kt=0;kt<8;kt++){
        short8 Ah = *(const short8*)((char*)uh + m*528 + kt*64 + q*16);
        short8 Al = *(const short8*)((char*)ul + m*528 + kt*64 + q*16);
        #pragma unroll
        for(int gg=0;gg<8;gg++){
          short8 Bh = (kt<4)? WiH[gg][kt] : WhH[gg][kt-4];
          short8 Bl = (kt<4)? WiL[gg][kt]
                            : *(const short8*)(smem + (size_t)(((w*8+gg)*4+(kt-4))*64+l)*16);
          acc[gg]=MFMA16(Ah,Bh,acc[gg]);
          acc[gg]=MFMA16(Ah,Bl,acc[gg]);
          acc[gg]=MFMA16(Al,Bh,acc[gg]);
        }
      }
      __syncthreads();   // all MFMA reads of u done -> safe to overwrite
      #pragma unroll
      for(int ngl=0;ngl<2;ngl++){
        const int col=(w*2+ngl)*16+m;
        #pragma unroll
        for(int r=0;r<4;r++){
          float I=fast_sig(acc[0*2+ngl][r]), F=fast_sig(acc[1*2+ngl][r]);
          float G=fast_tanh(acc[2*2+ngl][r]), O=fast_sig(acc[3*2+ngl][r]);
          c[ngl][r]=F*c[ngl][r]+I*G;
          float hv=O*fast_tanh(c[ngl][r]);
          uint16_t hb,lb; splitf(hv,hb,lb);
          const int row=q*4+r;
          uh[row*264+128+col]=hb; ul[row*264+128+col]=lb;
          if(first){
            size_t gi=((size_t)(rb+row)*T_+t)*128+col;
            plh[gi]=hb; pll[gi]=lb;
          } else if(t==T_-1){
            size_t gi=(size_t)(rb+row)*128+col;
            hTh[gi]=hb; hTl[gi]=lb;
          }
        }
      }
      if(dox) scat(nh0,nl0,nh1,nl1);
      __syncthreads();
    }
  };

  // ---- phase A: encoder layer 0 ----
  zeroH();
  { const float* src = x + ((size_t)(rb+srow)*T_+0)*128 + sc8;
    f32x4 v0=*(const f32x4*)src, v1=*(const f32x4*)(src+4);
    uint64_t a,b,cc,d; packf4(v0,a,b); packf4(v1,cc,d); scat(a,b,cc,d); }
  loadW(Wih0,Whh0,bih0,bhh0);
  #pragma unroll
  for(int i=0;i<2;i++)
    #pragma unroll
    for(int r=0;r<4;r++) c[i][r]=0.f;
  __syncthreads();
  scan(true);

  // ---- phase B: encoder layer 1 ----
  loadW(Wih1,Whh1,bih1,bhh1);
  zeroH();
  { size_t gi=((size_t)(rb+srow)*T_+0)*128+sc8;
    scat(*(const uint64_t*)(plh+gi), *(const uint64_t*)(pll+gi),
         *(const uint64_t*)(plh+gi+4), *(const uint64_t*)(pll+gi+4)); }
  #pragma unroll
  for(int i=0;i<2;i++)
    #pragma unroll
    for(int r=0;r<4;r++) c[i][r]=0.f;
  __syncthreads();
  scan(false);
}

// =====================  DECODER  =====================
// 64 blocks = 32 groups x 2 sides, 256 thr (4 waves, 1 block/CU).
// Side s owns h-cols [64s,64s+64); wave w owns cols cb+[16w,16w+16) of BOTH
// cells with all 4 gates -> nonlinearity is wave-local (no gx exchange).
// Weights: cell0 Wi+Wh hi+lo (256 regs) + cell1 Wi hi+lo (128 regs) in VGPRs;
// cell1 Whh hi+lo in LDS (128 KB, side's 256 rows).
// u K-slots: [0,128)=h1(latest)(=x_in; x0 at t=0), [128,256)=h0(latest).
// Halves exchanged via tagged u64 mailboxes (atomicExch / atomicAdd-poll).
// At t=0 cell1 skips kt<4 (h1(-1)=0 but slot holds x0).
__global__ __launch_bounds__(256,1) void dec_kernel(
    const float* __restrict__ Wih0, const float* __restrict__ Whh0,
    const float* __restrict__ bih0, const float* __restrict__ bhh0,
    const float* __restrict__ Wih1, const float* __restrict__ Whh1,
    const float* __restrict__ bih1, const float* __restrict__ bhh1,
    const uint16_t* __restrict__ hTh, const uint16_t* __restrict__ hTl,
    char* __restrict__ ws, float* __restrict__ out)
{
  extern __shared__ __align__(16) char smem[];
  const int tid=threadIdx.x, w=tid>>6, l=tid&63, q=l>>4, m=l&15;
  const int bid=blockIdx.x, g=bid>>1, s=bid&1, peer=bid^1;
  const int rb=g*16, cb=s*64;
  uint16_t* uh=(uint16_t*)(smem+U_H);
  uint16_t* ul=(uint16_t*)(smem+U_L);
  unsigned long long* mb0_own =(unsigned long long*)(ws + WS_MB0 + bid*8192);
  unsigned long long* mb0_peer=(unsigned long long*)(ws + WS_MB0 + peer*8192);
  unsigned long long* mb1_own =(unsigned long long*)(ws + WS_MB1 + bid*8192);
  unsigned long long* mb1_peer=(unsigned long long*)(ws + WS_MB1 + peer*8192);
  const int pb = 64-cb;   // peer col base

  short8 W0iH[4][4],W0iL[4][4],W0hH[4][4],W0hL[4][4],W1iH[4][4],W1iL[4][4];
  float b0[4], b1[4];
  #pragma unroll
  for(int gate=0;gate<4;gate++){
    const int row = gate*128 + cb + w*16 + m;
    const float* r0i = Wih0 + (size_t)row*128;
    const float* r0h = Whh0 + (size_t)row*128;
    const float* r1i = Wih1 + (size_t)row*128;
    const float* r1h = Whh1 + (size_t)row*128;
    #pragma unroll
    for(int kt=0;kt<4;kt++){
      load_frag2(r0i, kt*32+q*8, W0iH[gate][kt], W0iL[gate][kt]);
      load_frag2(r0h, kt*32+q*8, W0hH[gate][kt], W0hL[gate][kt]);
      load_frag2(r1i, kt*32+q*8, W1iH[gate][kt], W1iL[gate][kt]);
      short8 hh,hl; load_frag2(r1h, kt*32+q*8, hh,hl);
      *(short8*)(smem + (size_t)((((w*4+gate)*4+kt)*2+0)*64+l)*16)=hh;
      *(short8*)(smem + (size_t)((((w*4+gate)*4+kt)*2+1)*64+l)*16)=hl;
    }
    b0[gate]=bih0[row]+bhh0[row];
    b1[gate]=bih1[row]+bhh1[row];
  }
  // staging: slots [0,128)=hT (x_in(0)), slots [128,256)=0
  {
    const int srow=tid>>4, sc8=(tid&15)*8;
    *(uint64_t*)(uh+srow*264+128+sc8)=0ull;  *(uint64_t*)(uh+srow*264+128+sc8+4)=0ull;
    *(uint64_t*)(ul+srow*264+128+sc8)=0ull;  *(uint64_t*)(ul+srow*264+128+sc8+4)=0ull;
    size_t gi=(size_t)(rb+srow)*128+sc8;
    *(uint64_t*)(uh+srow*264+sc8)  =*(const uint64_t*)(hTh+gi);
    *(uint64_t*)(uh+srow*264+sc8+4)=*(const uint64_t*)(hTh+gi+4);
    *(uint64_t*)(ul+srow*264+sc8)  =*(const uint64_t*)(hTl+gi);
    *(uint64_t*)(ul+srow*264+sc8+4)=*(const uint64_t*)(hTl+gi+4);
  }
  float c0[4]={0,0,0,0}, c1[4]={0,0,0,0};
  const int gc = cb + w*16 + m;     // this lane's global h-column
  const int lc = w*16 + m;          // column within side (mailbox index)

  #pragma unroll 1
  for(int t=0;t<T_;t++){
    if(t>0){
      // ingest peer h1(t-1): tag == t
      #pragma unroll
      for(int i=0;i<4;i++){
        int idx=tid*4+i, row=idx>>6, col=idx&63;
        unsigned long long v;
        do { v = atomicAdd(mb1_peer+idx, 0ull);
             if((unsigned)(v>>32) == (unsigned)t) break;
             __builtin_amdgcn_s_sleep(1);
        } while(true);
        uh[row*264+pb+col]=(uint16_t)(v>>16); ul[row*264+pb+col]=(uint16_t)v;
      }
    }
    __syncthreads();                       // B1: u=[x_in|h0(t-1)] complete
    // ---- cell0 ----
    f32x4 acc[4];
    #pragma unroll
    for(int gate=0;gate<4;gate++) acc[gate]=splat4(b0[gate]);
    #pragma unroll
    for(int kt=0;kt<8;kt++){
      short8 Ah=*(const short8*)((char*)uh+m*528+kt*64+q*16);
      short8 Al=*(const short8*)((char*)ul+m*528+kt*64+q*16);
      #pragma unroll
      for(int gate=0;gate<4;gate++){
        short8 Bh=(kt<4)?W0iH[gate][kt]:W0hH[gate][kt-4];
        short8 Bl=(kt<4)?W0iL[gate][kt]:W0hL[gate][kt-4];
        acc[gate]=MFMA16(Ah,Bh,acc[gate]);
        acc[gate]=MFMA16(Ah,Bl,acc[gate]);
        acc[gate]=MFMA16(Al,Bh,acc[gate]);
      }
    }
    __syncthreads();                       // B2: cell0 u-reads done
    #pragma unroll
    for(int r=0;r<4;r++){
      float I=fast_sig(acc[0][r]), F=fast_sig(acc[1][r]);
      float G=fast_tanh(acc[2][r]), O=fast_sig(acc[3][r]);
      c0[r]=F*c0[r]+I*G;
      float hv=O*fast_tanh(c0[r]);
      uint16_t hb,lb; splitf(hv,hb,lb);
      const int row=q*4+r;
      uh[row*264+128+gc]=hb; ul[row*264+128+gc]=lb;
      unsigned long long tv = ((unsigned long long)(unsigned)(t+1)<<32)
                            | ((unsigned)hb<<16) | (unsigned)lb;
      atomicExch(mb0_own + row*64 + lc, tv);
    }
    // ingest peer h0(t): tag == t+1
    #pragma unroll
    for(int i=0;i<4;i++){
      int idx=tid*4+i, row=idx>>6, col=idx&63;
      unsigned long long v;
      do { v = atomicAdd(mb0_peer+idx, 0ull);
           if((unsigned)(v>>32) == (unsigned)(t+1)) break;
           __builtin_amdgcn_s_sleep(1);
      } while(true);
      uh[row*264+128+pb+col]=(uint16_t)(v>>16); ul[row*264+128+pb+col]=(uint16_t)v;
    }
    __syncthreads();                       // B3: u=[h1(t-1)|h0(t)] complete
    // ---- cell1 ----
    #pragma unroll
    for(int gate=0;gate<4;gate++) acc[gate]=splat4(b1[gate]);
    #pragma unroll
    for(int kt=0;kt<8;kt++){
      if(kt<4 && t==0) continue;   // h1(-1)=0: slot holds x0, skip Whh1 term
      short8 Ah=*(const short8*)((char*)uh+m*528+kt*64+q*16);
      short8 Al=*(const short8*)((char*)ul+m*528+kt*64+q*16);
      #pragma unroll
      for(int gate=0;gate<4;gate++){
        short8 Bh,Bl;
        if(kt<4){
          Bh=*(const short8*)(smem + (size_t)((((w*4+gate)*4+kt)*2+0)*64+l)*16);
          Bl=*(const short8*)(smem + (size_t)((((w*4+gate)*4+kt)*2+1)*64+l)*16);
        } else { Bh=W1iH[gate][kt-4]; Bl=W1iL[gate][kt-4]; }
        acc[gate]=MFMA16(Ah,Bh,acc[gate]);
        acc[gate]=MFMA16(Ah,Bl,acc[gate]);
        acc[gate]=MFMA16(Al,Bh,acc[gate]);
      }
    }
    __syncthreads();                       // B4: cell1 u-reads done
    #pragma unroll
    for(int r=0;r<4;r++){
      float I=fast_sig(acc[0][r]), F=fast_sig(acc[1][r]);
      float G=fast_tanh(acc[2][r]), O=fast_sig(acc[3][r]);
      c1[r]=F*c1[r]+I*G;
      float hv=O*fast_tanh(c1[r]);
      uint16_t hb,lb; splitf(hv,hb,lb);
      const int row=q*4+r;
      uh[row*264+gc]=hb; ul[row*264+gc]=lb;
      unsigned long long tv = ((unsigned long long)(unsigned)(t+1)<<32)
                            | ((unsigned)hb<<16) | (unsigned)lb;
      atomicExch(mb1_own + row*64 + lc, tv);
      out[((size_t)(rb+row)*T_+t)*128+gc]=hv;
    }
  }
}

// =====================  OUTPUT PROJECTION  =====================
__global__ __launch_bounds__(256,2) void outproj_kernel(
    const float* __restrict__ oW, const float* __restrict__ ob,
    float* __restrict__ out)
{
  __shared__ float As[16*132];
  const int tid=threadIdx.x, w=tid>>6, l=tid&63, q=l>>4, m=l&15;

  short8 BH[2][4], BL[2][4];
  float bias[2];
  #pragma unroll
  for(int tt=0;tt<2;tt++){
    const int j = (w*2+tt)*16+m;
    const float* rowp = oW + (size_t)j*128;
    #pragma unroll
    for(int kt=0;kt<4;kt++) load_frag2(rowp, kt*32+q*8, BH[tt][kt], BL[tt][kt]);
    bias[tt]=ob[j];
  }

  for(int s16=0;s16<16;s16++){
    const int strip = blockIdx.x*16 + s16;
    {
      const int row=tid>>4, col=(tid&15)*8;
      const float* src = out + ((size_t)strip*16+row)*128 + col;
      f32x4 a=*(const f32x4*)src, b=*(const f32x4*)(src+4);
      *(f32x4*)(As+row*132+col)=a; *(f32x4*)(As+row*132+col+4)=b;
    }
    __syncthreads();
    short8 Ah[4], Al[4];
    #pragma unroll
    for(int kt=0;kt<4;kt++){
      #pragma unroll
      for(int j=0;j<8;j++){
        uint16_t hb,lb; splitf(As[m*132+kt*32+q*8+j],hb,lb);
        Ah[kt][j]=(short)hb; Al[kt][j]=(short)lb;
      }
    }
    __syncthreads();
    f32x4 acc[2];
    acc[0]=splat4(bias[0]); acc[1]=splat4(bias[1]);
    #pragma unroll
    for(int kt=0;kt<4;kt++){
      #pragma unroll
      for(int tt=0;tt<2;tt++){
        acc[tt]=MFMA16(Ah[kt],BH[tt][kt],acc[tt]);
        acc[tt]=MFMA16(Ah[kt],BL[tt][kt],acc[tt]);
        acc[tt]=MFMA16(Al[kt],BH[tt][kt],acc[tt]);
      }
    }
    #pragma unroll
    for(int tt=0;tt<2;tt++){
      const int col = w*32+tt*16+m;
      #pragma unroll
      for(int r=0;r<4;r++)
        out[((size_t)strip*16+q*4+r)*128+col]=acc[tt][r];
    }
  }
}

extern "C" void kernel_launch(void* const* d_in, const int* in_sizes, int n_in,
                              void* d_out, int out_size, void* d_ws, size_t ws_size,
                              hipStream_t stream) {
  const float* x     = (const float*)d_in[0];
  const float* eWih0 = (const float*)d_in[1];
  const float* eWhh0 = (const float*)d_in[2];
  const float* ebih0 = (const float*)d_in[3];
  const float* ebhh0 = (const float*)d_in[4];
  const float* eWih1 = (const float*)d_in[5];
  const float* eWhh1 = (const float*)d_in[6];
  const float* ebih1 = (const float*)d_in[7];
  const float* ebhh1 = (const float*)d_in[8];
  const float* dWih0 = (const float*)d_in[9];
  const float* dWhh0 = (const float*)d_in[10];
  const float* dbih0 = (const float*)d_in[11];
  const float* dbhh0 = (const float*)d_in[12];
  const float* dWih1 = (const float*)d_in[13];
  const float* dWhh1 = (const float*)d_in[14];
  const float* dbih1 = (const float*)d_in[15];
  const float* dbhh1 = (const float*)d_in[16];
  const float* oW    = (const float*)d_in[17];
  const float* ob    = (const float*)d_in[18];
  float* out = (float*)d_out;
  char* ws = (char*)d_ws;

  (void)hipFuncSetAttribute((const void*)enc_kernel,
        hipFuncAttributeMaxDynamicSharedMemorySize, SCAN_SMEM);
  (void)hipFuncSetAttribute((const void*)dec_kernel,
        hipFuncAttributeMaxDynamicSharedMemorySize, SCAN_SMEM);

  // zero the tagged mailboxes (ws is poisoned 0xAA before every launch)
  hipMemsetAsync(d_ws, 0, WS_MB_BYTES, stream);

  uint16_t* plh = (uint16_t*)d_out;
  uint16_t* pll = plh + (size_t)512*T_*H_;
  uint16_t* hTh = (uint16_t*)(ws + WS_HTH);
  uint16_t* hTl = (uint16_t*)(ws + WS_HTL);

  enc_kernel<<<32, 256, SCAN_SMEM, stream>>>(
      x, eWih0, eWhh0, ebih0, ebhh0, eWih1, eWhh1, ebih1, ebhh1,
      plh, pll, hTh, hTl);
  dec_kernel<<<64, 256, SCAN_SMEM, stream>>>(
      dWih0, dWhh0, dbih0, dbhh0, dWih1, dWhh1, dbih1, dbhh1,
      hTh, hTl, ws, out);
  outproj_kernel<<<512, 256, 0, stream>>>(oW, ob, out);
}